// Round 7
// baseline (116.027 us; speedup 1.0000x reference)
//
#include <hip/hip_runtime.h>

// RankingLoss via target-rank counting sort (3 dispatches, no cooperative launch):
//   loss = (1/N) * sum_i [ K_i>0 ? (sum_{j: t[j]<t[i]} max(0, m - p[i] + p[j])) / K_i : 0 ]
// Dispatch 1: hipMemsetAsync zeroes {tie_ctr[N], acc, done} (contiguous in ws).
// Dispatch 2 (rank_scatter): strict rank K_i = #{t_j < t_i} via per-lane VALU
//   counting (2 VALU/pair); scatter pred into target-sorted slots, ties
//   resolved by atomic counter (set-invariant: phase B sums exactly the
//   prefix [0, K_i) = {j: t_j < t_i} regardless of tie order).
// Dispatch 3 (hinge_sorted): compare-free prefix hinge (3 VALU/pair, N^2/2
//   pairs), BALANCED: each block does the two complementary 8-slot groups
//   [8b,8b+8) and [N-8-8b,N-8b) so per-block work is ~constant. Block
//   partials go to acc via atomicAdd; the last block to finish (done
//   counter) writes d_out[0] = acc/N. Device-scope atomics only — no
//   dispatch-order or co-residency assumptions.

constexpr float MARGIN = 0.1f;
constexpr int T   = 256;   // threads per block
constexpr int R1  = 16;    // rows per block, pass 1 (grid = N/R1 = 1024)
constexpr int R2  = 8;     // slots per group, pass 2
constexpr int NB2 = 1024;  // pass-2 blocks (NB2 * 2 * R2 = N)

__global__ __launch_bounds__(T) void rank_scatter(const float* __restrict__ pred,
                                                  const float* __restrict__ target,
                                                  float* __restrict__ p_sorted,
                                                  int* __restrict__ K_sorted,
                                                  unsigned int* __restrict__ tie_ctr,
                                                  int n) {
    const int base = blockIdx.x * R1;

    float ti[R1];
    #pragma unroll
    for (int r = 0; r < R1; ++r) ti[r] = target[base + r];

    unsigned int cnt[R1];   // per-lane partial counts (VGPRs)
    #pragma unroll
    for (int r = 0; r < R1; ++r) cnt[r] = 0u;

    const float4* __restrict__ t4 = (const float4*)target;
    const int n4 = n >> 2;   // 4096, exact multiple of T: no partial waves

    for (int j = (int)threadIdx.x; j < n4; j += T) {
        const float4 tj = t4[j];
        #pragma unroll
        for (int r = 0; r < R1; ++r) {
            const float tir = ti[r];
            cnt[r] += (tj.x < tir) ? 1u : 0u;
            cnt[r] += (tj.y < tir) ? 1u : 0u;
            cnt[r] += (tj.z < tir) ? 1u : 0u;
            cnt[r] += (tj.w < tir) ? 1u : 0u;
        }
    }

    // Reduce per-lane counts: wave shuffle, then cross-wave via LDS.
    __shared__ unsigned int lc[T / 64][R1];
    const int lane = threadIdx.x & 63;
    const int wv   = threadIdx.x >> 6;

    #pragma unroll
    for (int r = 0; r < R1; ++r) {
        unsigned int c = cnt[r];
        #pragma unroll
        for (int off = 32; off > 0; off >>= 1) c += __shfl_down(c, off, 64);
        if (lane == 0) lc[wv][r] = c;
    }
    __syncthreads();

    if ((int)threadIdx.x < R1) {
        const int r = threadIdx.x;
        const unsigned int strict = lc[0][r] + lc[1][r] + lc[2][r] + lc[3][r];
        // Unique slot within the tie group (internal order irrelevant).
        const int slot = (int)strict + (int)atomicAdd(&tie_ctr[strict], 1u);
        p_sorted[slot] = pred[base + r];
        K_sorted[slot] = (int)strict;
    }
}

__global__ __launch_bounds__(T) void hinge_sorted(const float* __restrict__ p_sorted,
                                                  const int* __restrict__ K_sorted,
                                                  float* __restrict__ acc,
                                                  unsigned int* __restrict__ done,
                                                  float* __restrict__ out,
                                                  int n, float inv_n) {
    const int lane = threadIdx.x & 63;
    const int wv   = threadIdx.x >> 6;

    __shared__ float ls[T / 64][R2];
    __shared__ float row_val[R2];

    float block_total = 0.f;

    #pragma unroll
    for (int g = 0; g < 2; ++g) {
        // Two complementary groups: per-block pair-work ~ constant (~N).
        const int base = (g == 0) ? (int)blockIdx.x * R2
                                  : n - R2 - (int)blockIdx.x * R2;

        float c[R2];
        int   K[R2];   // monotone non-decreasing in slot
        #pragma unroll
        for (int r = 0; r < R2; ++r) {
            K[r] = K_sorted[base + r];
            c[r] = MARGIN - p_sorted[base + r];
        }
        const int Kmin = K[0];
        const int Kmax = K[R2 - 1];

        float sum[R2];
        #pragma unroll
        for (int r = 0; r < R2; ++r) sum[r] = 0.f;

        // Main loop: compare-free over the common prefix [0, 4*(Kmin/4)).
        const float4* __restrict__ p4 = (const float4*)p_sorted;
        const int n4m = Kmin >> 2;
        for (int j = (int)threadIdx.x; j < n4m; j += T) {
            const float4 p = p4[j];
            #pragma unroll
            for (int r = 0; r < R2; ++r) {
                const float cr = c[r];
                sum[r] += fmaxf(0.f, cr + p.x);
                sum[r] += fmaxf(0.f, cr + p.y);
                sum[r] += fmaxf(0.f, cr + p.z);
                sum[r] += fmaxf(0.f, cr + p.w);
            }
        }
        // Predicated tail: j in [4*(Kmin/4), Kmax) — a handful of elements.
        for (int j = (n4m << 2) + (int)threadIdx.x; j < Kmax; j += T) {
            const float pj = p_sorted[j];
            #pragma unroll
            for (int r = 0; r < R2; ++r) {
                sum[r] += (j < K[r]) ? fmaxf(0.f, c[r] + pj) : 0.f;
            }
        }

        __syncthreads();   // protect LDS reuse across the two groups
        #pragma unroll
        for (int r = 0; r < R2; ++r) {
            float s = sum[r];
            #pragma unroll
            for (int off = 32; off > 0; off >>= 1) s += __shfl_down(s, off, 64);
            if (lane == 0) ls[wv][r] = s;
        }
        __syncthreads();

        if ((int)threadIdx.x < R2) {
            const int r = threadIdx.x;
            const float s = ls[0][r] + ls[1][r] + ls[2][r] + ls[3][r];
            row_val[r] = (K[r] > 0) ? (s / (float)K[r]) : 0.f;
        }
        __syncthreads();

        if (threadIdx.x == 0) {
            #pragma unroll
            for (int r = 0; r < R2; ++r) block_total += row_val[r];
        }
    }

    // Last-block-finishes pattern (device-scope atomics; no ordering assumptions).
    if (threadIdx.x == 0) {
        atomicAdd(acc, block_total);
        __threadfence();
        const unsigned int old = atomicAdd(done, 1u);
        if (old == (unsigned int)(gridDim.x - 1)) {
            const float total = atomicAdd(acc, 0.0f);   // atomic read of final sum
            out[0] = total * inv_n;
        }
    }
}

extern "C" void kernel_launch(void* const* d_in, const int* in_sizes, int n_in,
                              void* d_out, int out_size, void* d_ws, size_t ws_size,
                              hipStream_t stream) {
    const float* pred   = (const float*)d_in[0];
    const float* target = (const float*)d_in[1];
    const int n = in_sizes[0];                 // 16384

    // ws layout: p_sorted [0,4N) | K_sorted [4N,8N) | tie_ctr [8N,12N) | acc | done
    float*        p_sorted = (float*)d_ws;
    int*          K_sorted = (int*)((char*)d_ws + (size_t)n * 4);
    unsigned int* tie_ctr  = (unsigned int*)((char*)d_ws + (size_t)n * 8);
    float*        acc      = (float*)((char*)d_ws + (size_t)n * 12);
    unsigned int* done     = (unsigned int*)((char*)d_ws + (size_t)n * 12 + 4);

    // One memset covers tie_ctr + acc + done (contiguous).
    hipMemsetAsync(tie_ctr, 0, (size_t)n * 4 + 8, stream);

    rank_scatter<<<n / R1, T, 0, stream>>>(pred, target, p_sorted, K_sorted, tie_ctr, n);
    hinge_sorted<<<NB2, T, 0, stream>>>(p_sorted, K_sorted, acc, done,
                                        (float*)d_out, n, 1.0f / (float)n);
}